// Round 5
// baseline (542.818 us; speedup 1.0000x reference)
//
#include <hip/hip_runtime.h>

// y = x @ block_diag(M repeated), g = 128.
// Y[R,128] = X[R,128] * M[128,128], R = 524288.
// Operand-swapped MFMA: D = (M^T frag)·(X frag) so each lane's 4 acc values
// are 4 CONSECUTIVE OUTPUT COLS -> f32x4 stores (was 32 scalar dword stores).
// 2-stage register pipeline: next tile's loads issued before current compute.

typedef float f32x4 __attribute__((ext_vector_type(4)));
typedef short s16x8 __attribute__((ext_vector_type(8)));

#define GSZ   128
#define PITCH 136   // 272B row pitch; 2-way LDS aliasing only (~free)

// fp32 -> bf16 round-to-nearest-even
static __device__ __forceinline__ unsigned short f2bf(float f) {
  union { float f; unsigned int u; } v; v.f = f;
  unsigned int u = v.u;
  return (unsigned short)((u + 0x7fffu + ((u >> 16) & 1u)) >> 16);
}

static __device__ __forceinline__ void cvt8(f32x4 f0, f32x4 f1, s16x8& av) {
  av[0] = (short)f2bf(f0[0]); av[1] = (short)f2bf(f0[1]);
  av[2] = (short)f2bf(f0[2]); av[3] = (short)f2bf(f0[3]);
  av[4] = (short)f2bf(f1[0]); av[5] = (short)f2bf(f1[1]);
  av[6] = (short)f2bf(f1[2]); av[7] = (short)f2bf(f1[3]);
}

__global__ __launch_bounds__(256, 4)
void ff_block_gemm(const float* __restrict__ X, const float* __restrict__ M,
                   float* __restrict__ Y, int ntiles) {
  // MT[c][k] = bf16(M[k][c])
  __shared__ unsigned short MT[GSZ * PITCH];

  const int tid = threadIdx.x;
  #pragma unroll 4
  for (int it = 0; it < 64; ++it) {
    int idx = it * 256 + tid;               // coalesced read of M
    MT[(idx & 127) * PITCH + (idx >> 7)] = f2bf(M[idx]);
  }
  __syncthreads();

  const int w  = tid >> 6;   // wave 0..3
  const int l  = tid & 63;
  const int lr = l & 15;     // X-row within 16 (B-col / D-col)
  const int kg = l >> 4;     // k-group 0..3 (8 contiguous k each)
  const int grid = gridDim.x;

  int t = blockIdx.x;

  // prologue: load tile t
  f32x4 cur[8];
  {
    const float* xp = X + (size_t)(t * 64 + w * 16 + lr) * GSZ + kg * 8;
    #pragma unroll
    for (int ks = 0; ks < 4; ++ks) {
      cur[2 * ks]     = *(const f32x4*)(xp + ks * 32);
      cur[2 * ks + 1] = *(const f32x4*)(xp + ks * 32 + 4);
    }
  }

  while (t < ntiles) {
    const int tn = t + grid;

    // issue NEXT tile's loads first — latency hides under current compute
    f32x4 nxt[8];
    if (tn < ntiles) {
      const float* xp = X + (size_t)(tn * 64 + w * 16 + lr) * GSZ + kg * 8;
      #pragma unroll
      for (int ks = 0; ks < 4; ++ks) {
        nxt[2 * ks]     = *(const f32x4*)(xp + ks * 32);
        nxt[2 * ks + 1] = *(const f32x4*)(xp + ks * 32 + 4);
      }
    }

    // X fragments (B-operand): col = lane&15 = X-row, k = 8*(lane>>4)+i
    s16x8 a[4];
    #pragma unroll
    for (int ks = 0; ks < 4; ++ks) cvt8(cur[2 * ks], cur[2 * ks + 1], a[ks]);

    f32x4 acc[8];
    #pragma unroll
    for (int nt = 0; nt < 8; ++nt) acc[nt] = (f32x4){0.f, 0.f, 0.f, 0.f};

    #pragma unroll
    for (int ks = 0; ks < 4; ++ks) {
      #pragma unroll
      for (int nt = 0; nt < 8; ++nt) {
        // M^T fragment (A-operand): row = lane&15 = output col, k = 8*(lane>>4)+i
        const s16x8 b = *(const s16x8*)&MT[(nt * 16 + lr) * PITCH + ks * 32 + kg * 8];
        acc[nt] = __builtin_amdgcn_mfma_f32_16x16x32_bf16(b, a[ks], acc[nt], 0, 0, 0);
      }
    }

    // D = Y^T chunk: lane (lr,kg) holds Y[r0+lr][nt*16 + kg*4 + q], q=0..3
    // -> 4 consecutive floats: vectorized nontemporal store (no L2 allocate/RMW)
    float* yp = Y + (size_t)(t * 64 + w * 16 + lr) * GSZ + kg * 4;
    #pragma unroll
    for (int nt = 0; nt < 8; ++nt)
      __builtin_nontemporal_store(acc[nt], (f32x4*)(yp + nt * 16));

    #pragma unroll
    for (int i = 0; i < 8; ++i) cur[i] = nxt[i];
    t = tn;
  }
}

extern "C" void kernel_launch(void* const* d_in, const int* in_sizes, int n_in,
                              void* d_out, int out_size, void* d_ws, size_t ws_size,
                              hipStream_t stream) {
  const float* X = (const float*)d_in[0];
  const float* M = (const float*)d_in[1];
  float* Y = (float*)d_out;
  const int R = in_sizes[0] / GSZ;       // 524288 rows
  const int ntiles = R / 64;             // 8192 tiles of 64 rows
  int grid = ntiles < 1024 ? ntiles : 1024;  // 4 blocks/CU, persistent
  hipLaunchKernelGGL(ff_block_gemm, dim3(grid), dim3(256), 0, stream,
                     X, M, Y, ntiles);
}

// Round 7
// 437.211 us; speedup vs baseline: 1.2415x; 1.2415x over previous
//
#include <hip/hip_runtime.h>

// y = x @ block_diag(M repeated), g = 128.
// Y[R,128] = X[R,128] * M[128,128], R = 524288.
// Swapped MFMA (D = M^T-frag · X-frag). Store path: wave-private LDS
// transpose (intra-wave, no barrier) -> fully coalesced full-sector
// global stores (4 rows x 256B contiguous per instruction).
// Register double-buffer on X loads; launch_bounds(256,2) so the
// prefetch actually stays in VGPRs (R5: cap 128 made compiler sink it).

typedef float f32x4 __attribute__((ext_vector_type(4)));
typedef short s16x8 __attribute__((ext_vector_type(8)));

#define GSZ     128
#define MTPITCH 136   // shorts per MT row: 272B pitch, 2-way LDS aliasing (~free)
#define YPITCH  68    // f32 per Ybuf row slot: 272B pitch -> conflict-free patterns

// fp32 -> bf16 round-to-nearest-even
static __device__ __forceinline__ unsigned short f2bf(float f) {
  union { float f; unsigned int u; } v; v.f = f;
  unsigned int u = v.u;
  return (unsigned short)((u + 0x7fffu + ((u >> 16) & 1u)) >> 16);
}

static __device__ __forceinline__ void cvt8(f32x4 f0, f32x4 f1, s16x8& av) {
  av[0] = (short)f2bf(f0[0]); av[1] = (short)f2bf(f0[1]);
  av[2] = (short)f2bf(f0[2]); av[3] = (short)f2bf(f0[3]);
  av[4] = (short)f2bf(f1[0]); av[5] = (short)f2bf(f1[1]);
  av[6] = (short)f2bf(f1[2]); av[7] = (short)f2bf(f1[3]);
}

__global__ __launch_bounds__(256, 2)
void ff_block_gemm(const float* __restrict__ X, const float* __restrict__ M,
                   float* __restrict__ Y, int ntiles) {
  // MT[c][k] = bf16(M[k][c])
  __shared__ unsigned short MT[GSZ * MTPITCH];
  // per-wave Y staging: 16 rows x 64 cols f32 (one col-half at a time)
  __shared__ float YB[4][16 * YPITCH];

  const int tid = threadIdx.x;
  #pragma unroll 4
  for (int it = 0; it < 64; ++it) {
    int idx = it * 256 + tid;               // coalesced read of M
    MT[(idx & 127) * MTPITCH + (idx >> 7)] = f2bf(M[idx]);
  }
  __syncthreads();

  const int w  = tid >> 6;   // wave 0..3
  const int l  = tid & 63;
  const int lr = l & 15;     // X-row within 16 (D col)
  const int kg = l >> 4;     // k-group 0..3
  const int grid = gridDim.x;
  float* const yb = &YB[w][0];

  int t = blockIdx.x;

  // prologue: load tile t
  f32x4 cur[8];
  if (t < ntiles) {
    const float* xp = X + (size_t)(t * 64 + w * 16 + lr) * GSZ + kg * 8;
    #pragma unroll
    for (int ks = 0; ks < 4; ++ks) {
      cur[2 * ks]     = *(const f32x4*)(xp + ks * 32);
      cur[2 * ks + 1] = *(const f32x4*)(xp + ks * 32 + 4);
    }
  }

  for (; t < ntiles; t += grid) {
    const int tn = t + grid;

    // issue NEXT tile's loads first — latency hides under current compute
    f32x4 nxt[8];
    if (tn < ntiles) {
      const float* xp = X + (size_t)(tn * 64 + w * 16 + lr) * GSZ + kg * 8;
      #pragma unroll
      for (int ks = 0; ks < 4; ++ks) {
        nxt[2 * ks]     = *(const f32x4*)(xp + ks * 32);
        nxt[2 * ks + 1] = *(const f32x4*)(xp + ks * 32 + 4);
      }
    }

    // X fragments (B-operand): col = lane&15 = X-row, k = 8*(lane>>4)+i
    s16x8 a[4];
    #pragma unroll
    for (int ks = 0; ks < 4; ++ks) cvt8(cur[2 * ks], cur[2 * ks + 1], a[ks]);

    f32x4 acc[8];
    #pragma unroll
    for (int nt = 0; nt < 8; ++nt) acc[nt] = (f32x4){0.f, 0.f, 0.f, 0.f};

    #pragma unroll
    for (int ks = 0; ks < 4; ++ks) {
      #pragma unroll
      for (int nt = 0; nt < 8; ++nt) {
        // M^T fragment (A-operand): row = lane&15 = output col
        const s16x8 b = *(const s16x8*)&MT[(nt * 16 + lr) * MTPITCH + ks * 32 + kg * 8];
        acc[nt] = __builtin_amdgcn_mfma_f32_16x16x32_bf16(b, a[ks], acc[nt], 0, 0, 0);
      }
    }

    // Epilogue: lane (lr,kg) holds Y[r0+lr][nt*16 + kg*4 + q], q=0..3.
    // Stage one 64-col half in wave-private LDS, re-read linearly, store
    // fully coalesced (per instr: 4 rows x 256B contiguous, full sectors).
    const size_t rowbase = (size_t)t * 64 + w * 16;
    #pragma unroll
    for (int h = 0; h < 2; ++h) {
      #pragma unroll
      for (int n2 = 0; n2 < 4; ++n2) {
        // bank-group (lr + 4*n2 + kg) & 7 -> uniform
        *(f32x4*)&yb[lr * YPITCH + n2 * 16 + kg * 4] = acc[h * 4 + n2];
      }
      #pragma unroll
      for (int i = 0; i < 4; ++i) {
        const int r = i * 4 + (l >> 4);      // 4 rows per instr
        const int c = (l & 15) * 4;          // f32 col within the 64-col half
        f32x4 v = *(const f32x4*)&yb[r * YPITCH + c];
        *(f32x4*)(Y + (rowbase + r) * GSZ + h * 64 + c) = v;
      }
    }

    #pragma unroll
    for (int i = 0; i < 8; ++i) cur[i] = nxt[i];
  }
}

extern "C" void kernel_launch(void* const* d_in, const int* in_sizes, int n_in,
                              void* d_out, int out_size, void* d_ws, size_t ws_size,
                              hipStream_t stream) {
  const float* X = (const float*)d_in[0];
  const float* M = (const float*)d_in[1];
  float* Y = (float*)d_out;
  const int R = in_sizes[0] / GSZ;       // 524288 rows
  const int ntiles = R / 64;             // 8192 tiles of 64 rows
  int grid = ntiles < 2048 ? ntiles : 2048;  // 3 blocks/CU resident (LDS 52KB)
  hipLaunchKernelGGL(ff_block_gemm, dim3(grid), dim3(256), 0, stream,
                     X, M, Y, ntiles);
}